// Round 6
// baseline (1139.320 us; speedup 1.0000x reference)
//
#include <hip/hip_runtime.h>
#include <cstddef>

#define IN_CH 1024
#define NT    81
#define KGRID 7
#define NBINS 49
#define HH    100
#define WW    100
#define NPIX  (HH*WW)
#define NREG  1024
#define COLB  82            // gemm column group per bin: 81 real + 1 zero pad
#define NCOL  (NBINS*COLB)  // 4018 gemm columns
#define NPADW 4096          // padded N (16 tiles of 256)
#define SBIN  84            // sm per-bin stride in BYTES (int8), 4-aligned rows
#define SROWB (NBINS*SBIN)  // 4116 B per pixel row
#define NSC   2560          // scale table floats (80*32)
#define PXB   ((NPIX + 31) / 32)        // 313 prep_x col-blocks
#define PXG   (PXB * (IN_CH / 128))     // 2504 prep_x blocks
#define PREPG (PXG + NPADW / 8)         // + 512 prep_w blocks (8 rows each)

#define GM_T  40            // m tiles of 256 (10240 >= 10000)
#define GN_T  16            // n tiles of 256
#define NKT   32            // K tiles of 32 (K=1024)

typedef unsigned short ushortT;
typedef short bf16x8 __attribute__((ext_vector_type(8)));
typedef float f32x4  __attribute__((ext_vector_type(4)));

static __device__ __forceinline__ unsigned short f2bf(float f) {
    unsigned int u = __builtin_bit_cast(unsigned int, f);
    return (unsigned short)((u + 0x7fffu + ((u >> 16) & 1u)) >> 16);
}

// async global->LDS, 16B per lane; LDS dest = wave-uniform base + lane*16
static __device__ __forceinline__ void gld_lds16(const ushortT* g, ushortT* l) {
    __builtin_amdgcn_global_load_lds(
        (__attribute__((address_space(1))) void*)(unsigned long long)(uintptr_t)g,
        (__attribute__((address_space(3))) void*)(unsigned int)(unsigned long long)(uintptr_t)l,
        16, 0, 0);
}

static __device__ __forceinline__ void barf() {
    asm volatile("" ::: "memory");
    __builtin_amdgcn_s_barrier();
    asm volatile("" ::: "memory");
}

// ---------- fused prep: x (C,P) fp32 -> xbT (P,C) bf16  |  conv_w -> Wr -------------
__global__ __launch_bounds__(256) void prep_fused(const float* __restrict__ x,
                                                  ushortT* __restrict__ xbT,
                                                  const float* __restrict__ conv_w,
                                                  ushortT* __restrict__ Wr) {
    __shared__ float tile[128][33];
    const int tid = threadIdx.x;
    const int bid = blockIdx.x;
    if (bid < PXG) {
        const int p0 = (bid % PXB) * 32;
        const int c0 = (bid / PXB) * 128;
        const int pl = tid & 31;
        const int cg = tid >> 5;          // 0..7
        const int p = p0 + pl;
#pragma unroll
        for (int it = 0; it < 16; ++it) {
            const int c = it * 8 + cg;
            tile[c][pl] = (p < NPIX) ? x[(size_t)(c0 + c) * NPIX + p] : 0.0f;
        }
        __syncthreads();
#pragma unroll
        for (int pass = 0; pass < 2; ++pass) {
            const int pix = pass * 16 + (tid >> 4);
            const int cb  = (tid & 15) * 8;
            if (p0 + pix < NPIX) {
                uint4 pk;
                pk.x = (unsigned int)f2bf(tile[cb + 0][pix]) | ((unsigned int)f2bf(tile[cb + 1][pix]) << 16);
                pk.y = (unsigned int)f2bf(tile[cb + 2][pix]) | ((unsigned int)f2bf(tile[cb + 3][pix]) << 16);
                pk.z = (unsigned int)f2bf(tile[cb + 4][pix]) | ((unsigned int)f2bf(tile[cb + 5][pix]) << 16);
                pk.w = (unsigned int)f2bf(tile[cb + 6][pix]) | ((unsigned int)f2bf(tile[cb + 7][pix]) << 16);
                *(uint4*)(xbT + (size_t)(p0 + pix) * IN_CH + c0 + cb) = pk;
            }
        }
    } else {
        const int row0 = (bid - PXG) * 8;
        const int c    = tid * 4;
#pragma unroll
        for (int rr = 0; rr < 8; ++rr) {
            const int row = row0 + rr;
            const int bin = row / COLB;
            const int t   = row - bin * COLB;
            uint2 pk; pk.x = 0; pk.y = 0;
            if (bin < NBINS && t < NT) {
                const float4 v = *(const float4*)(conv_w + ((size_t)(t * NBINS + bin)) * IN_CH + c);
                pk.x = (unsigned int)f2bf(v.x) | ((unsigned int)f2bf(v.y) << 16);
                pk.y = (unsigned int)f2bf(v.z) | ((unsigned int)f2bf(v.w) << 16);
            }
            *(uint2*)(Wr + (size_t)row * IN_CH + c) = pk;
        }
    }
}

// ---------- GEMM: 256x256, BK=32, 64KB LDS -> 2 blocks/CU (cross-block overlap) -----
// R5 model closure: 1 block/CU made MfmaUtil = 39% active x (2.5/3 load quant) = 32%
// in EVERY schedule variant (barriers empty the whole CU; makespan = ceil(640/256)).
// Fix is occupancy, not scheduling: BK 64->32 halves LDS to 64KB -> 2 blocks/CU,
// 4 waves/SIMD; one block's barrier/vmcnt stalls hide under the other's MFMAs
// (m103/m114 mechanism), and 640 blocks schedule into 512 slots (smooth tail).
// BK=32 swizzle: slot = kq ^ (row&3) ^ ((row>>2)&3) -> worst 2-way (free, m136);
// applied inverse on global source (rule #21), same on ds_read.
__global__ __launch_bounds__(512, 4) void gemm_sm(const ushortT* __restrict__ xbT,
                                                  const ushortT* __restrict__ Wr,
                                                  unsigned char* __restrict__ sm,
                                                  float* __restrict__ scales) {
    __shared__ ushortT lA[2][8192];   // [buf][256 rows][32 cols] swizzled (16KB each)
    __shared__ ushortT lB[2][8192];

    const int tid  = threadIdx.x;
    const int lane = tid & 63;
    const int w    = tid >> 6;        // 0..7
    const int wm   = w & 1;           // m half (128 rows)
    const int wn   = w >> 1;          // 0..3 (64 cols)

    // bijective XCD swizzle: 640 = 8 * 80
    const int bid   = blockIdx.x;
    const int sw    = (bid & 7) * 80 + (bid >> 3);
    const int mtile = sw >> 4;        // 0..39
    const int ntile = sw & 15;        // 0..15
    const int p0 = mtile * 256;
    const int n0 = ntile * 256;

    // ---- staging: chunk r in {0,1} covers rows (r*8+w)*16 + (lane>>2), slot lane&3.
    // LDS dest linear (chunkbase*32 + lane*8 elems); source col = inverse-swizzled.
    const int crow = lane >> 2;                                   // 0..15 in chunk
    const int sw2  = ((lane & 3) ^ (crow & 3) ^ ((crow >> 2) & 3)) << 3;
    const ushortT* gAr[2];
    const ushortT* gBr[2];
    int dstR[2];
#pragma unroll
    for (int r = 0; r < 2; ++r) {
        const int row = (r * 8 + w) * 16 + crow;                  // 0..255
        int p = p0 + row; if (p > NPIX - 1) p = NPIX - 1;
        gAr[r] = xbT + (size_t)p * IN_CH + sw2;
        gBr[r] = Wr + (size_t)(n0 + row) * IN_CH + sw2;
        dstR[r] = (r * 8 + w) * 512 + lane * 8;
    }
#define STG_A(bb, r, T) gld_lds16(gAr[r] + (size_t)(T) * 32, &lA[bb][dstR[r]])
#define STG_B(bb, r, T) gld_lds16(gBr[r] + (size_t)(T) * 32, &lB[bb][dstR[r]])

    // ---- fragment read geometry ----
    const int m_l = lane & 15;
    const int kq  = lane >> 4;                                    // 0..3
    const int phs = ((kq ^ (m_l & 3) ^ ((m_l >> 2) & 3)) << 3);   // phys slot * 8
    const int arow = (wm * 128 + m_l) * 32;
    const int brow = (wn * 64 + m_l) * 32;

#define RD_A(bb, mq) { _Pragma("unroll") for (int mt = 0; mt < 4; ++mt) \
        af[mt] = *(const bf16x8*)(&lA[bb][arow + ((mq) * 64 + mt * 16) * 32 + phs]); }
#define RD_B(dst, bb, nq) { _Pragma("unroll") for (int nt = 0; nt < 2; ++nt) \
        dst[nt] = *(const bf16x8*)(&lB[bb][brow + ((nq) * 32 + nt * 16) * 32 + phs]); }
#define MM(mq, B, nq) { _Pragma("unroll") for (int mt = 0; mt < 4; ++mt) \
        _Pragma("unroll") for (int nt = 0; nt < 2; ++nt) \
        acc[mq][mt][nq][nt] = __builtin_amdgcn_mfma_f32_16x16x32_bf16(af[mt], B[nt], acc[mq][mt][nq][nt], 0, 0, 0); }
#define PMM(mq, B, nq) { __builtin_amdgcn_s_setprio(1); MM(mq, B, nq); __builtin_amdgcn_s_setprio(0); }

    f32x4 acc[2][4][2][2];
#pragma unroll
    for (int a = 0; a < 2; ++a)
#pragma unroll
        for (int b = 0; b < 4; ++b)
#pragma unroll
            for (int c = 0; c < 2; ++c)
#pragma unroll
                for (int d = 0; d < 2; ++d) acc[a][b][c][d] = (f32x4){0.f, 0.f, 0.f, 0.f};

    bf16x8 af[4], bf0[2], bf1[2];

    // ---- prologue: stage tile0 (buf0), tile1 (buf1); wait tile0 (tile1 in flight) ----
    STG_A(0, 0, 0); STG_A(0, 1, 0); STG_B(0, 0, 0); STG_B(0, 1, 0);
    STG_A(1, 0, 1); STG_A(1, 1, 1); STG_B(1, 0, 1); STG_B(1, 1, 1);
    asm volatile("s_waitcnt vmcnt(4)" ::: "memory");
    __builtin_amdgcn_s_barrier();
    asm volatile("" ::: "memory");

#pragma unroll 2
    for (int kt = 0; kt < NKT; ++kt) {
        const int b = kt & 1;
        const bool st = (kt < NKT - 2);
        // ---- phase A: all 12 ds_reads of buf b, 3 MFMA quadrants ----
        RD_A(b, 0);
        RD_B(bf0, b, 0);
        RD_B(bf1, b, 1);
        PMM(0, bf0, 0);
        PMM(0, bf1, 1);
        RD_A(b, 1);
        PMM(1, bf1, 1);
        asm volatile("s_waitcnt lgkmcnt(0)" ::: "memory");   // reads of buf b complete
        barf();                                              // bar1
        // ---- phase B: stage tile kt+2 into buf b; MM(1,0) overlaps; counted drain ----
        if (st) {
            STG_A(b, 0, kt + 2); STG_A(b, 1, kt + 2);
            STG_B(b, 0, kt + 2); STG_B(b, 1, kt + 2);
        }
        PMM(1, bf0, 0);
        if (st) asm volatile("s_waitcnt vmcnt(4)" ::: "memory");
        else    asm volatile("s_waitcnt vmcnt(0)" ::: "memory");
        barf();                                              // bar2: tile kt+1 resident
    }

    // ---- epilogue: per-quadrant (128x128) amax -> int8 quantize ----
    __syncthreads();
    float am = 0.0f;
#pragma unroll
    for (int mq = 0; mq < 2; ++mq)
#pragma unroll
        for (int mt = 0; mt < 4; ++mt)
#pragma unroll
            for (int nq = 0; nq < 2; ++nq)
#pragma unroll
                for (int nt = 0; nt < 2; ++nt)
#pragma unroll
                    for (int rg = 0; rg < 4; ++rg)
                        am = fmaxf(am, fabsf(acc[mq][mt][nq][nt][rg]));
#pragma unroll
    for (int off = 32; off > 0; off >>= 1) am = fmaxf(am, __shfl_xor(am, off));
    float* red = (float*)lA;
    if (lane == 0) red[w] = am;
    __syncthreads();
    // quadrant of wave w: (qm = wm, qn = wn>>1); partner wave = w ^ 2
    const float qam = fmaxf(fmaxf(red[w], red[w ^ 2]), 1e-30f);
    const float inv = 127.0f / qam;
    if (lane == 0 && (wn & 1) == 0)
        scales[(mtile * 2 + wm) * 32 + ntile * 2 + (wn >> 1)] = qam * (1.0f / 127.0f);

    const int prow0 = p0 + wm * 128 + kq * 4;
    const int ncol0 = n0 + wn * 64 + m_l;
    int  coloff[2][2];
    bool cok[2][2];
#pragma unroll
    for (int nq = 0; nq < 2; ++nq)
#pragma unroll
        for (int nt = 0; nt < 2; ++nt) {
            const int n = ncol0 + nq * 32 + nt * 16;
            cok[nq][nt] = (n < NCOL);
            coloff[nq][nt] = n + 2 * (n / COLB);
        }
#pragma unroll
    for (int mq = 0; mq < 2; ++mq)
#pragma unroll
        for (int mt = 0; mt < 4; ++mt)
#pragma unroll
            for (int rg = 0; rg < 4; ++rg) {
                const int p = prow0 + mq * 64 + mt * 16 + rg;
                if (p < NPIX) {
                    unsigned char* rowp = sm + (size_t)p * SROWB;
#pragma unroll
                    for (int nq = 0; nq < 2; ++nq)
#pragma unroll
                        for (int nt = 0; nt < 2; ++nt)
                            if (cok[nq][nt]) {
                                const int q = __float2int_rn(acc[mq][mt][nq][nt][rg] * inv);
                                rowp[coloff[nq][nt]] = (unsigned char)(signed char)q;
                            }
                }
            }
#undef STG_A
#undef STG_B
#undef RD_A
#undef RD_B
#undef MM
#undef PMM
}

// ---------- pooling: ONE block per region -------------------------------------------
__global__ __launch_bounds__(256) void pool_kernel(const unsigned char* __restrict__ sm,
                                                   const float* __restrict__ scales,
                                                   const float* __restrict__ regions,
                                                   const float* __restrict__ conv_b,
                                                   float* __restrict__ out) {
    __shared__ int   rowo[28]; __shared__ float roww[28];
    __shared__ int   coli[28]; __shared__ float colw[28];
    __shared__ int   pofs[800];
    __shared__ float pw[800];
    __shared__ int   pptb[800];   // (pix>>7)*32
    __shared__ int   pnb[800];    // bin*82
    __shared__ float part[40][100];
    const int tid = threadIdx.x;
    const int r = blockIdx.x;

    if (tid < 28) {
        const float4 reg = *(const float4*)(regions + (size_t)r * 4);
        const float top = (reg.x - reg.z * 0.5f) * (float)HH;
        const float bh  = reg.z * ((float)HH / (float)KGRID);
        const int u = tid >> 2, i = tid & 3;
        const int s = i >> 1, hi = i & 1;
        float y = top + ((float)u + ((float)s + 0.5f) * 0.5f) * bh;
        y = fminf(fmaxf(y, 0.0f), (float)(HH - 1));
        const float y0f = floorf(y);
        const int y0 = (int)y0f;
        const float wy1 = y - y0f;
        rowo[tid] = (hi ? min(y0 + 1, HH - 1) : y0) * WW;
        roww[tid] = hi ? wy1 : (1.0f - wy1);
    } else if (tid >= 32 && tid < 60) {
        const float4 reg = *(const float4*)(regions + (size_t)r * 4);
        const float left = (reg.y - reg.w * 0.5f) * (float)WW;
        const float bw   = reg.w * ((float)WW / (float)KGRID);
        const int idx = tid - 32;
        const int v = idx >> 2, j = idx & 3;
        const int s = j >> 1, hi = j & 1;
        float xx = left + ((float)v + ((float)s + 0.5f) * 0.5f) * bw;
        xx = fminf(fmaxf(xx, 0.0f), (float)(WW - 1));
        const float x0f = floorf(xx);
        const int x0 = (int)x0f;
        const float wx1 = xx - x0f;
        coli[idx] = hi ? min(x0 + 1, WW - 1) : x0;
        colw[idx] = hi ? wx1 : (1.0f - wx1);
    }
    __syncthreads();
#pragma unroll
    for (int base = 0; base < 800; base += 256) {
        const int idx = base + tid;
        if (idx < 800) {
            if (idx < 784) {                 // 49 bins * 16 taps
                const int bin = idx >> 4, tap = idx & 15;
                const int u = bin / KGRID, v = bin - u * KGRID;
                const int i = tap >> 2, j = tap & 3;
                const int pix = rowo[u * 4 + i] + coli[v * 4 + j];
                pofs[idx] = pix * SROWB + bin * SBIN;     // BYTE offset, 4-aligned
                pw[idx]   = roww[u * 4 + i] * colw[v * 4 + j] * (1.0f / 196.0f);
                pptb[idx] = (pix >> 7) * 32;
                pnb[idx]  = bin * COLB;
            } else {                          // zero-weight padding taps
                pofs[idx] = 0;
                pw[idx]   = 0.0f;
                pptb[idx] = 0;
                pnb[idx]  = 0;
            }
        }
    }
    __syncthreads();

    const int lane = tid & 63, w = tid >> 6;
    const int sub  = lane / 6;              // 0..9 active, lanes 60..63 idle
    const int cg   = lane - sub * 6;        // 0..5 -> channels cg*16..+15
    if (sub < 10) {
        const int str = w * 10 + sub;       // 0..39

        float acc[16];
#pragma unroll
        for (int ch = 0; ch < 16; ++ch) acc[ch] = 0.0f;

        uint4 v[4], vn[4];
#pragma unroll
        for (int it = 0; it < 4; ++it)
            v[it] = *(const uint4*)(sm + pofs[it * 40 + str] + cg * 16);

        for (int gp = 0; gp < 5; ++gp) {
            if (gp < 4) {
#pragma unroll
                for (int it = 0; it < 4; ++it)
                    vn[it] = *(const uint4*)(sm + pofs[(gp * 4 + 4 + it) * 40 + str] + cg * 16);
            }
#pragma unroll
            for (int it = 0; it < 4; ++it) {
                const int l  = (gp * 4 + it) * 40 + str;
                const float wt = pw[l];
                const int nb  = pnb[l] + cg * 16;   // n of channel 0
                const int nt0 = nb >> 7;
                const int rr  = nb & 127;
                const float s0 = scales[pptb[l] + nt0];
                const float s1 = scales[pptb[l] + nt0 + 1];
                const float w0 = wt * s0, w1 = wt * s1;
                const unsigned int uu[4] = {v[it].x, v[it].y, v[it].z, v[it].w};
#pragma unroll
                for (int b = 0; b < 4; ++b) {
#pragma unroll
                    for (int k = 0; k < 4; ++k) {
                        const int ch = b * 4 + k;
                        const int q = (int)(signed char)((uu[b] >> (k * 8)) & 0xff);
                        acc[ch] += ((rr < 128 - ch) ? w0 : w1) * (float)q;
                    }
                }
            }
#pragma unroll
            for (int it = 0; it < 4; ++it) v[it] = vn[it];
        }
#pragma unroll
        for (int b = 0; b < 4; ++b) {
            float4 p4;
            p4.x = acc[b * 4]; p4.y = acc[b * 4 + 1];
            p4.z = acc[b * 4 + 2]; p4.w = acc[b * 4 + 3];
            *(float4*)&part[str][cg * 16 + b * 4] = p4;
        }
    }
    __syncthreads();
    if (tid < NT) {
        float vv = 0.f;
#pragma unroll
        for (int s = 0; s < 40; ++s) vv += part[s][tid];
        float bsum = 0.f;
        for (int bin = 0; bin < NBINS; ++bin) bsum += conv_b[tid * NBINS + bin];
        out[(size_t)r * NT + tid] = vv + bsum * (1.0f / (float)NBINS);
    }
}

// =======================  fallback path (round-1 kernel)  ==========================
__global__ __launch_bounds__(256) void xpose_kernel(const float* __restrict__ x,
                                                    float* __restrict__ xt) {
    __shared__ float tile[32][33];
    const int p0 = blockIdx.x * 32;
    const int c0 = blockIdx.y * 32;
    const int tx = threadIdx.x;
    const int ty = threadIdx.y;
#pragma unroll
    for (int k = 0; k < 32; k += 8) {
        const int p = p0 + tx;
        if (p < NPIX) tile[ty + k][tx] = x[(size_t)(c0 + ty + k) * NPIX + p];
    }
    __syncthreads();
#pragma unroll
    for (int k = 0; k < 32; k += 8) {
        const int p = p0 + ty + k;
        if (p < NPIX) xt[(size_t)p * IN_CH + (c0 + tx)] = tile[tx][ty + k];
    }
}

template <bool XPOSED>
__global__ __launch_bounds__(256) void psroi_kernel(
    const float* __restrict__ xsrc, const float* __restrict__ regions,
    const float* __restrict__ conv_w, const float* __restrict__ conv_b,
    float* __restrict__ out) {
    __shared__ float w_lds[32 * 96];
    __shared__ float g_lds[32 * 64];
    __shared__ int   rowoff[64][4];
    __shared__ float rowwf[64][4];
    __shared__ int   colidx[64][4];
    __shared__ float colwf[64][4];
    const int tid = threadIdx.x;
    const int bin = blockIdx.x >> 4;
    const int rg  = blockIdx.x & 15;
    const int u = bin / KGRID, v = bin % KGRID;
    const int r0 = rg * 64;
    if (tid < 64) {
        const float4 reg = *(const float4*)(regions + (size_t)(r0 + tid) * 4);
        const float top  = (reg.x - reg.z * 0.5f) * (float)HH;
        const float left = (reg.y - reg.w * 0.5f) * (float)WW;
        const float bh = reg.z * ((float)HH / (float)KGRID);
        const float bw = reg.w * ((float)WW / (float)KGRID);
        const float scale = 1.0f / 196.0f;
#pragma unroll
        for (int s = 0; s < 2; s++) {
            const float off = (s + 0.5f) * 0.5f;
            float yy = top + ((float)u + off) * bh;
            yy = fminf(fmaxf(yy, 0.0f), (float)(HH - 1));
            const float y0f = floorf(yy);
            const int y0 = (int)y0f;
            const float wy1 = yy - y0f;
            rowoff[tid][2 * s] = y0 * WW;
            rowoff[tid][2 * s + 1] = min(y0 + 1, HH - 1) * WW;
            rowwf[tid][2 * s] = (1.0f - wy1) * scale;
            rowwf[tid][2 * s + 1] = wy1 * scale;
            float xx = left + ((float)v + off) * bw;
            xx = fminf(fmaxf(xx, 0.0f), (float)(WW - 1));
            const float x0f = floorf(xx);
            const int x0 = (int)x0f;
            const float wx1 = xx - x0f;
            colidx[tid][2 * s] = x0;
            colidx[tid][2 * s + 1] = min(x0 + 1, WW - 1);
            colwf[tid][2 * s] = 1.0f - wx1;
            colwf[tid][2 * s + 1] = wx1;
        }
    }
    const int ri = tid & 15, tq = tid >> 4, rb = tid >> 2, cq = tid & 3;
    float acc[4][6];
#pragma unroll
    for (int m = 0; m < 4; m++)
#pragma unroll
        for (int k = 0; k < 6; k++) acc[m][k] = 0.0f;
    for (int chunk = 0; chunk < IN_CH / 32; chunk++) {
        const int c0 = chunk * 32;
        __syncthreads();
#pragma unroll
        for (int it = 0; it < 12; it++) {
            const int idx = it * 256 + tid;
            const int t = idx >> 5, c = idx & 31;
            float val = 0.0f;
            if (t < NT) val = conv_w[(size_t)(t * NBINS + bin) * IN_CH + c0 + c];
            w_lds[c * 96 + t] = val;
        }
        const int cbase = c0 + cq * 8;
        float g8[8];
#pragma unroll
        for (int cc = 0; cc < 8; cc++) g8[cc] = 0.0f;
#pragma unroll
        for (int i = 0; i < 4; i++) {
            const int ro = rowoff[rb][i];
            const float wy = rowwf[rb][i];
#pragma unroll
            for (int j = 0; j < 4; j++) {
                const int pix = ro + colidx[rb][j];
                const float wv = wy * colwf[rb][j];
                if (XPOSED) {
                    const float4* p = (const float4*)(xsrc + (size_t)pix * IN_CH + cbase);
                    const float4 a = p[0]; const float4 b = p[1];
                    g8[0] += wv * a.x; g8[1] += wv * a.y; g8[2] += wv * a.z; g8[3] += wv * a.w;
                    g8[4] += wv * b.x; g8[5] += wv * b.y; g8[6] += wv * b.z; g8[7] += wv * b.w;
                } else {
#pragma unroll
                    for (int cc = 0; cc < 8; cc++)
                        g8[cc] += wv * xsrc[(size_t)(cbase + cc) * NPIX + pix];
                }
            }
        }
#pragma unroll
        for (int cc = 0; cc < 8; cc++) g_lds[(cq * 8 + cc) * 64 + rb] = g8[cc];
        __syncthreads();
#pragma unroll 4
        for (int c = 0; c < 32; c++) {
            float wv[6];
#pragma unroll
            for (int k = 0; k < 6; k++) wv[k] = w_lds[c * 96 + tq * 6 + k];
            const float4 gq = *(const float4*)&g_lds[c * 64 + ri * 4];
            const float gm[4] = {gq.x, gq.y, gq.z, gq.w};
#pragma unroll
            for (int m = 0; m < 4; m++)
#pragma unroll
                for (int k = 0; k < 6; k++) acc[m][k] += gm[m] * wv[k];
        }
    }
    const float invK2 = 1.0f / 49.0f;
#pragma unroll
    for (int k = 0; k < 6; k++) {
        const int t = tq * 6 + k;
        if (t < NT) {
            const float bterm = conv_b[t * NBINS + bin] * invK2;
#pragma unroll
            for (int m = 0; m < 4; m++) {
                const int rr = r0 + ri * 4 + m;
                atomicAdd(&out[(size_t)rr * NT + t], acc[m][k] + bterm);
            }
        }
    }
}

extern "C" void kernel_launch(void* const* d_in, const int* in_sizes, int n_in,
                              void* d_out, int out_size, void* d_ws, size_t ws_size,
                              hipStream_t stream) {
    const float* x       = (const float*)d_in[0];
    const float* regions = (const float*)d_in[1];
    const float* conv_w  = (const float*)d_in[2];
    const float* conv_b  = (const float*)d_in[3];
    float* out = (float*)d_out;

    const size_t sz_xbT = (size_t)NPIX * IN_CH * 2;          // 20,480,000
    const size_t sz_Wr  = (size_t)NPADW * IN_CH * 2;         //  8,388,608
    const size_t sz_sm  = (size_t)NPIX * SROWB + 256;        // 41,160,000 + slack
    const size_t sz_sc  = (size_t)NSC * sizeof(float);       // 10,240
    const size_t need   = sz_xbT + sz_Wr + sz_sm + sz_sc;    // ~70.0 MB

    if (ws_size >= need) {
        ushortT* xbT = (ushortT*)d_ws;
        ushortT* Wr  = (ushortT*)((char*)d_ws + sz_xbT);
        unsigned char* sm = (unsigned char*)d_ws + sz_xbT + sz_Wr;
        float* scales = (float*)((char*)d_ws + sz_xbT + sz_Wr + sz_sm);
        prep_fused<<<dim3(PREPG), 256, 0, stream>>>(x, xbT, conv_w, Wr);
        gemm_sm<<<dim3(GM_T * GN_T), 512, 0, stream>>>(xbT, Wr, sm, scales);
        pool_kernel<<<dim3(NREG), 256, 0, stream>>>(sm, scales, regions, conv_b, out);
    } else {
        hipMemsetAsync(out, 0, (size_t)out_size * sizeof(float), stream);
        const size_t xt_bytes = (size_t)NPIX * IN_CH * sizeof(float);
        const dim3 mainGrid(NBINS * 16);
        if (ws_size >= xt_bytes) {
            float* xt = (float*)d_ws;
            xpose_kernel<<<dim3((NPIX + 31) / 32, IN_CH / 32), dim3(32, 8), 0, stream>>>(x, xt);
            psroi_kernel<true><<<mainGrid, 256, 0, stream>>>(xt, regions, conv_w, conv_b, out);
        } else {
            psroi_kernel<false><<<mainGrid, 256, 0, stream>>>(x, regions, conv_w, conv_b, out);
        }
    }
}

// Round 7
// 228.334 us; speedup vs baseline: 4.9897x; 4.9897x over previous
//
#include <hip/hip_runtime.h>
#include <cstddef>

#define IN_CH 1024
#define NT    81
#define KGRID 7
#define NBINS 49
#define HH    100
#define WW    100
#define NPIX  (HH*WW)
#define NREG  1024
#define COLB  82            // gemm column group per bin: 81 real + 1 zero pad
#define NCOL  (NBINS*COLB)  // 4018 gemm columns
#define NPADW 4096          // padded N (16 tiles of 256)
#define SBIN  84            // sm per-bin stride in BYTES (int8), 4-aligned rows
#define SROWB (NBINS*SBIN)  // 4116 B per pixel row
#define NSC   2560          // scale table floats (80*32)
#define PXB   ((NPIX + 31) / 32)        // 313 prep_x col-blocks
#define PXG   (PXB * (IN_CH / 128))     // 2504 prep_x blocks
#define PREPG (PXG + NPADW / 8)         // + 512 prep_w blocks (8 rows each)

#define GM_T  40            // m tiles of 256 (10240 >= 10000)
#define GN_T  16            // n tiles of 256
#define NKT   16            // K tiles of 64 (K=1024)

typedef unsigned short ushortT;
typedef short bf16x8 __attribute__((ext_vector_type(8)));
typedef float f32x4  __attribute__((ext_vector_type(4)));

static __device__ __forceinline__ unsigned short f2bf(float f) {
    unsigned int u = __builtin_bit_cast(unsigned int, f);
    return (unsigned short)((u + 0x7fffu + ((u >> 16) & 1u)) >> 16);
}

// async global->LDS, 16B per lane; LDS dest = wave-uniform base + lane*16
static __device__ __forceinline__ void gld_lds16(const ushortT* g, ushortT* l) {
    __builtin_amdgcn_global_load_lds(
        (__attribute__((address_space(1))) void*)(unsigned long long)(uintptr_t)g,
        (__attribute__((address_space(3))) void*)(unsigned int)(unsigned long long)(uintptr_t)l,
        16, 0, 0);
}

static __device__ __forceinline__ void barf() {
    asm volatile("" ::: "memory");
    __builtin_amdgcn_s_barrier();
    asm volatile("" ::: "memory");
}

// ---------- fused prep: x (C,P) fp32 -> xbT (P,C) bf16  |  conv_w -> Wr -------------
__global__ __launch_bounds__(256) void prep_fused(const float* __restrict__ x,
                                                  ushortT* __restrict__ xbT,
                                                  const float* __restrict__ conv_w,
                                                  ushortT* __restrict__ Wr) {
    __shared__ float tile[128][33];
    const int tid = threadIdx.x;
    const int bid = blockIdx.x;
    if (bid < PXG) {
        const int p0 = (bid % PXB) * 32;
        const int c0 = (bid / PXB) * 128;
        const int pl = tid & 31;
        const int cg = tid >> 5;          // 0..7
        const int p = p0 + pl;
#pragma unroll
        for (int it = 0; it < 16; ++it) {
            const int c = it * 8 + cg;
            tile[c][pl] = (p < NPIX) ? x[(size_t)(c0 + c) * NPIX + p] : 0.0f;
        }
        __syncthreads();
#pragma unroll
        for (int pass = 0; pass < 2; ++pass) {
            const int pix = pass * 16 + (tid >> 4);
            const int cb  = (tid & 15) * 8;
            if (p0 + pix < NPIX) {
                uint4 pk;
                pk.x = (unsigned int)f2bf(tile[cb + 0][pix]) | ((unsigned int)f2bf(tile[cb + 1][pix]) << 16);
                pk.y = (unsigned int)f2bf(tile[cb + 2][pix]) | ((unsigned int)f2bf(tile[cb + 3][pix]) << 16);
                pk.z = (unsigned int)f2bf(tile[cb + 4][pix]) | ((unsigned int)f2bf(tile[cb + 5][pix]) << 16);
                pk.w = (unsigned int)f2bf(tile[cb + 6][pix]) | ((unsigned int)f2bf(tile[cb + 7][pix]) << 16);
                *(uint4*)(xbT + (size_t)(p0 + pix) * IN_CH + c0 + cb) = pk;
            }
        }
    } else {
        const int row0 = (bid - PXG) * 8;
        const int c    = tid * 4;
#pragma unroll
        for (int rr = 0; rr < 8; ++rr) {
            const int row = row0 + rr;
            const int bin = row / COLB;
            const int t   = row - bin * COLB;
            uint2 pk; pk.x = 0; pk.y = 0;
            if (bin < NBINS && t < NT) {
                const float4 v = *(const float4*)(conv_w + ((size_t)(t * NBINS + bin)) * IN_CH + c);
                pk.x = (unsigned int)f2bf(v.x) | ((unsigned int)f2bf(v.y) << 16);
                pk.y = (unsigned int)f2bf(v.z) | ((unsigned int)f2bf(v.w) << 16);
            }
            *(uint2*)(Wr + (size_t)row * IN_CH + c) = pk;
        }
    }
}

// ---------- GEMM: 256x256 tile, BK=64, 8 waves — R3 single-barrier variant ----------
// Best measured gemm of the session (102.2-102.7us, MfmaUtil 34-35, conflicts 0).
// R6 lesson baked in: acc[2][4][2][2] = 128 VGPR/lane -> launch_bounds min-waves MUST
// stay at 2/SIMD (512,2). Any tighter bound spills accumulators to scratch (R6:
// VGPR_Count 64, 3.5GB scratch traffic, 10x slowdown).
//   P1{RD_A0,RD_B0+B1,MM} P2{MM} bar P3{RD_A1,stageB(kt+2),MM} bar
//   P4{MM,stageA(kt+2),vmcnt(8)} bar
__global__ __launch_bounds__(512, 2) void gemm_sm(const ushortT* __restrict__ xbT,
                                                  const ushortT* __restrict__ Wr,
                                                  unsigned char* __restrict__ sm,
                                                  float* __restrict__ scales) {
    __shared__ ushortT lA[2][16384];   // [buf][256 rows][64 cols] swizzled
    __shared__ ushortT lB[2][16384];

    const int tid  = threadIdx.x;
    const int lane = tid & 63;
    const int w    = tid >> 6;        // 0..7
    const int wm   = w & 1;           // m half (128 rows)
    const int wn   = w >> 1;          // 0..3 (64 cols)

    // bijective XCD swizzle: 640 = 8 * 80
    const int bid   = blockIdx.x;
    const int sw    = (bid & 7) * 80 + (bid >> 3);
    const int mtile = sw >> 4;        // 0..39
    const int ntile = sw & 15;        // 0..15
    const int p0 = mtile * 256;
    const int n0 = ntile * 256;

    // ---- staging geometry (linear LDS dest, inverse-swizzled global source) ----
    const int l3   = lane >> 3;                       // 0..7 = row&7 of staged row
    const int srco = ((lane & 7) ^ l3) << 3;          // source col element offset
    const int w2   = w * 2;

    const ushortT* gA[2][2];
    const ushortT* gB[2][2];
    int dstA[2][2];
#pragma unroll
    for (int h = 0; h < 2; ++h)
#pragma unroll
        for (int it = 0; it < 2; ++it) {
            const int hr = (w2 + it) * 8 + l3;        // 0..127 within half
            int p = p0 + h * 128 + hr; if (p > NPIX - 1) p = NPIX - 1;
            gA[h][it] = xbT + (size_t)p * IN_CH + srco;
            gB[h][it] = Wr + (size_t)(n0 + h * 128 + hr) * IN_CH + srco;
            dstA[h][it] = h * 8192 + (w2 + it) * 512 + lane * 8;
        }

#define STAGE_A(bb, h, T) { gld_lds16(gA[h][0] + (size_t)(T) * 64, &lA[bb][dstA[h][0]]); \
                            gld_lds16(gA[h][1] + (size_t)(T) * 64, &lA[bb][dstA[h][1]]); }
#define STAGE_B(bb, h, T) { gld_lds16(gB[h][0] + (size_t)(T) * 64, &lB[bb][dstA[h][0]]); \
                            gld_lds16(gB[h][1] + (size_t)(T) * 64, &lB[bb][dstA[h][1]]); }

    // ---- fragment read geometry ----
    const int m_l = lane & 15;
    const int kq  = lane >> 4;                        // 0..3
    const int ph0 = ((kq) ^ (lane & 7)) << 3;         // kh=0 phys slot * 8
    const int ph1 = ((4 + kq) ^ (lane & 7)) << 3;     // kh=1
    const int arow = (wm * 128 + m_l) * 64;
    const int brow = (wn * 64 + m_l) * 64;

#define RD_A(bb, mq) { _Pragma("unroll") for (int mt = 0; mt < 4; ++mt) { \
        const int ro = arow + ((mq) * 64 + mt * 16) * 64; \
        af[mt][0] = *(const bf16x8*)(&lA[bb][ro + ph0]); \
        af[mt][1] = *(const bf16x8*)(&lA[bb][ro + ph1]); } }
#define RD_B(dst, bb, nq) { _Pragma("unroll") for (int nt = 0; nt < 2; ++nt) { \
        const int ro = brow + ((nq) * 32 + nt * 16) * 64; \
        dst[nt][0] = *(const bf16x8*)(&lB[bb][ro + ph0]); \
        dst[nt][1] = *(const bf16x8*)(&lB[bb][ro + ph1]); } }
#define MM(mq, B, nq) { _Pragma("unroll") for (int mt = 0; mt < 4; ++mt) \
        _Pragma("unroll") for (int nt = 0; nt < 2; ++nt) { \
        acc[mq][mt][nq][nt] = __builtin_amdgcn_mfma_f32_16x16x32_bf16(af[mt][0], B[nt][0], acc[mq][mt][nq][nt], 0, 0, 0); \
        acc[mq][mt][nq][nt] = __builtin_amdgcn_mfma_f32_16x16x32_bf16(af[mt][1], B[nt][1], acc[mq][mt][nq][nt], 0, 0, 0); } }

    f32x4 acc[2][4][2][2];
#pragma unroll
    for (int a = 0; a < 2; ++a)
#pragma unroll
        for (int b = 0; b < 4; ++b)
#pragma unroll
            for (int c = 0; c < 2; ++c)
#pragma unroll
                for (int d = 0; d < 2; ++d) acc[a][b][c][d] = (f32x4){0.f, 0.f, 0.f, 0.f};

    bf16x8 af[4][2], bf0[2][2], bf1[2][2];

    // ---- prologue: stage tiles 0 and 1 fully; wait tile 0 (tile 1 in flight) ----
    STAGE_A(0, 0, 0); STAGE_A(0, 1, 0); STAGE_B(0, 0, 0); STAGE_B(0, 1, 0);
    STAGE_A(1, 0, 1); STAGE_A(1, 1, 1); STAGE_B(1, 0, 1); STAGE_B(1, 1, 1);
    asm volatile("s_waitcnt vmcnt(8)" ::: "memory");
    __builtin_amdgcn_s_barrier();
    asm volatile("" ::: "memory");

#pragma unroll 2
    for (int kt = 0; kt < NKT; ++kt) {
        const int b = kt & 1;
        // ---- P1: reads A(mq0) + B(both nq); MM(0,0). no barrier ----
        RD_A(b, 0);
        RD_B(bf0, b, 0);
        RD_B(bf1, b, 1);
        __builtin_amdgcn_s_setprio(1);
        MM(0, bf0, 0);
        __builtin_amdgcn_s_setprio(0);
        // ---- P2: MM(0,1). barrier: all B-reads of buf b now consumed ----
        __builtin_amdgcn_s_setprio(1);
        MM(0, bf1, 1);
        __builtin_amdgcn_s_setprio(0);
        barf();
        // ---- P3: reads A(mq1); stage B(kt+2) into freed lB[b]; MM(1,1) ----
        RD_A(b, 1);
        if (kt < NKT - 2) { STAGE_B(b, 0, kt + 2); STAGE_B(b, 1, kt + 2); }
        __builtin_amdgcn_s_setprio(1);
        MM(1, bf1, 1);
        __builtin_amdgcn_s_setprio(0);
        barf();   // all A-reads of buf b consumed
        // ---- P4: MM(1,0); stage A(kt+2); counted vmcnt(8) ----
        __builtin_amdgcn_s_setprio(1);
        MM(1, bf0, 0);
        __builtin_amdgcn_s_setprio(0);
        if (kt < NKT - 2) {
            STAGE_A(b, 0, kt + 2); STAGE_A(b, 1, kt + 2);
            asm volatile("s_waitcnt vmcnt(8)" ::: "memory");
        } else {
            asm volatile("s_waitcnt vmcnt(0)" ::: "memory");
        }
        __builtin_amdgcn_s_barrier();
        asm volatile("" ::: "memory");
    }

    // ---- epilogue: per-quadrant (128x128) amax -> int8 quantize ----
    __syncthreads();
    float am = 0.0f;
#pragma unroll
    for (int mq = 0; mq < 2; ++mq)
#pragma unroll
        for (int mt = 0; mt < 4; ++mt)
#pragma unroll
            for (int nq = 0; nq < 2; ++nq)
#pragma unroll
                for (int nt = 0; nt < 2; ++nt)
#pragma unroll
                    for (int rg = 0; rg < 4; ++rg)
                        am = fmaxf(am, fabsf(acc[mq][mt][nq][nt][rg]));
#pragma unroll
    for (int off = 32; off > 0; off >>= 1) am = fmaxf(am, __shfl_xor(am, off));
    float* red = (float*)lA;
    if (lane == 0) red[w] = am;
    __syncthreads();
    // quadrant of wave w: (qm = wm, qn = wn>>1); partner wave = w ^ 2
    const float qam = fmaxf(fmaxf(red[w], red[w ^ 2]), 1e-30f);
    const float inv = 127.0f / qam;
    if (lane == 0 && (wn & 1) == 0)
        scales[(mtile * 2 + wm) * 32 + ntile * 2 + (wn >> 1)] = qam * (1.0f / 127.0f);

    const int prow0 = p0 + wm * 128 + kq * 4;
    const int ncol0 = n0 + wn * 64 + m_l;
    int  coloff[2][2];
    bool cok[2][2];
#pragma unroll
    for (int nq = 0; nq < 2; ++nq)
#pragma unroll
        for (int nt = 0; nt < 2; ++nt) {
            const int n = ncol0 + nq * 32 + nt * 16;
            cok[nq][nt] = (n < NCOL);
            coloff[nq][nt] = n + 2 * (n / COLB);
        }
#pragma unroll
    for (int mq = 0; mq < 2; ++mq)
#pragma unroll
        for (int mt = 0; mt < 4; ++mt)
#pragma unroll
            for (int rg = 0; rg < 4; ++rg) {
                const int p = prow0 + mq * 64 + mt * 16 + rg;
                if (p < NPIX) {
                    unsigned char* rowp = sm + (size_t)p * SROWB;
#pragma unroll
                    for (int nq = 0; nq < 2; ++nq)
#pragma unroll
                        for (int nt = 0; nt < 2; ++nt)
                            if (cok[nq][nt]) {
                                const int q = __float2int_rn(acc[mq][mt][nq][nt][rg] * inv);
                                rowp[coloff[nq][nt]] = (unsigned char)(signed char)q;
                            }
                }
            }
#undef STAGE_A
#undef STAGE_B
#undef RD_A
#undef RD_B
#undef MM
}

// ---------- pooling: ONE block per region -------------------------------------------
__global__ __launch_bounds__(256) void pool_kernel(const unsigned char* __restrict__ sm,
                                                   const float* __restrict__ scales,
                                                   const float* __restrict__ regions,
                                                   const float* __restrict__ conv_b,
                                                   float* __restrict__ out) {
    __shared__ int   rowo[28]; __shared__ float roww[28];
    __shared__ int   coli[28]; __shared__ float colw[28];
    __shared__ int   pofs[800];
    __shared__ float pw[800];
    __shared__ int   pptb[800];   // (pix>>7)*32
    __shared__ int   pnb[800];    // bin*82
    __shared__ float part[40][100];
    const int tid = threadIdx.x;
    const int r = blockIdx.x;

    if (tid < 28) {
        const float4 reg = *(const float4*)(regions + (size_t)r * 4);
        const float top = (reg.x - reg.z * 0.5f) * (float)HH;
        const float bh  = reg.z * ((float)HH / (float)KGRID);
        const int u = tid >> 2, i = tid & 3;
        const int s = i >> 1, hi = i & 1;
        float y = top + ((float)u + ((float)s + 0.5f) * 0.5f) * bh;
        y = fminf(fmaxf(y, 0.0f), (float)(HH - 1));
        const float y0f = floorf(y);
        const int y0 = (int)y0f;
        const float wy1 = y - y0f;
        rowo[tid] = (hi ? min(y0 + 1, HH - 1) : y0) * WW;
        roww[tid] = hi ? wy1 : (1.0f - wy1);
    } else if (tid >= 32 && tid < 60) {
        const float4 reg = *(const float4*)(regions + (size_t)r * 4);
        const float left = (reg.y - reg.w * 0.5f) * (float)WW;
        const float bw   = reg.w * ((float)WW / (float)KGRID);
        const int idx = tid - 32;
        const int v = idx >> 2, j = idx & 3;
        const int s = j >> 1, hi = j & 1;
        float xx = left + ((float)v + ((float)s + 0.5f) * 0.5f) * bw;
        xx = fminf(fmaxf(xx, 0.0f), (float)(WW - 1));
        const float x0f = floorf(xx);
        const int x0 = (int)x0f;
        const float wx1 = xx - x0f;
        coli[idx] = hi ? min(x0 + 1, WW - 1) : x0;
        colw[idx] = hi ? wx1 : (1.0f - wx1);
    }
    __syncthreads();
#pragma unroll
    for (int base = 0; base < 800; base += 256) {
        const int idx = base + tid;
        if (idx < 800) {
            if (idx < 784) {                 // 49 bins * 16 taps
                const int bin = idx >> 4, tap = idx & 15;
                const int u = bin / KGRID, v = bin - u * KGRID;
                const int i = tap >> 2, j = tap & 3;
                const int pix = rowo[u * 4 + i] + coli[v * 4 + j];
                pofs[idx] = pix * SROWB + bin * SBIN;     // BYTE offset, 4-aligned
                pw[idx]   = roww[u * 4 + i] * colw[v * 4 + j] * (1.0f / 196.0f);
                pptb[idx] = (pix >> 7) * 32;
                pnb[idx]  = bin * COLB;
            } else {                          // zero-weight padding taps
                pofs[idx] = 0;
                pw[idx]   = 0.0f;
                pptb[idx] = 0;
                pnb[idx]  = 0;
            }
        }
    }
    __syncthreads();

    const int lane = tid & 63, w = tid >> 6;
    const int sub  = lane / 6;              // 0..9 active, lanes 60..63 idle
    const int cg   = lane - sub * 6;        // 0..5 -> channels cg*16..+15
    if (sub < 10) {
        const int str = w * 10 + sub;       // 0..39

        float acc[16];
#pragma unroll
        for (int ch = 0; ch < 16; ++ch) acc[ch] = 0.0f;

        uint4 v[4], vn[4];
#pragma unroll
        for (int it = 0; it < 4; ++it)
            v[it] = *(const uint4*)(sm + pofs[it * 40 + str] + cg * 16);

        for (int gp = 0; gp < 5; ++gp) {
            if (gp < 4) {
#pragma unroll
                for (int it = 0; it < 4; ++it)
                    vn[it] = *(const uint4*)(sm + pofs[(gp * 4 + 4 + it) * 40 + str] + cg * 16);
            }
#pragma unroll
            for (int it = 0; it < 4; ++it) {
                const int l  = (gp * 4 + it) * 40 + str;
                const float wt = pw[l];
                const int nb  = pnb[l] + cg * 16;   // n of channel 0
                const int nt0 = nb >> 7;
                const int rr  = nb & 127;
                const float s0 = scales[pptb[l] + nt0];
                const float s1 = scales[pptb[l] + nt0 + 1];
                const float w0 = wt * s0, w1 = wt * s1;
                const unsigned int uu[4] = {v[it].x, v[it].y, v[it].z, v[it].w};
#pragma unroll
                for (int b = 0; b < 4; ++b) {
#pragma unroll
                    for (int k = 0; k < 4; ++k) {
                        const int ch = b * 4 + k;
                        const int q = (int)(signed char)((uu[b] >> (k * 8)) & 0xff);
                        acc[ch] += ((rr < 128 - ch) ? w0 : w1) * (float)q;
                    }
                }
            }
#pragma unroll
            for (int it = 0; it < 4; ++it) v[it] = vn[it];
        }
#pragma unroll
        for (int b = 0; b < 4; ++b) {
            float4 p4;
            p4.x = acc[b * 4]; p4.y = acc[b * 4 + 1];
            p4.z = acc[b * 4 + 2]; p4.w = acc[b * 4 + 3];
            *(float4*)&part[str][cg * 16 + b * 4] = p4;
        }
    }
    __syncthreads();
    if (tid < NT) {
        float vv = 0.f;
#pragma unroll
        for (int s = 0; s < 40; ++s) vv += part[s][tid];
        float bsum = 0.f;
        for (int bin = 0; bin < NBINS; ++bin) bsum += conv_b[tid * NBINS + bin];
        out[(size_t)r * NT + tid] = vv + bsum * (1.0f / (float)NBINS);
    }
}

// =======================  fallback path (round-1 kernel)  ==========================
__global__ __launch_bounds__(256) void xpose_kernel(const float* __restrict__ x,
                                                    float* __restrict__ xt) {
    __shared__ float tile[32][33];
    const int p0 = blockIdx.x * 32;
    const int c0 = blockIdx.y * 32;
    const int tx = threadIdx.x;
    const int ty = threadIdx.y;
#pragma unroll
    for (int k = 0; k < 32; k += 8) {
        const int p = p0 + tx;
        if (p < NPIX) tile[ty + k][tx] = x[(size_t)(c0 + ty + k) * NPIX + p];
    }
    __syncthreads();
#pragma unroll
    for (int k = 0; k < 32; k += 8) {
        const int p = p0 + ty + k;
        if (p < NPIX) xt[(size_t)p * IN_CH + (c0 + tx)] = tile[tx][ty + k];
    }
}

template <bool XPOSED>
__global__ __launch_bounds__(256) void psroi_kernel(
    const float* __restrict__ xsrc, const float* __restrict__ regions,
    const float* __restrict__ conv_w, const float* __restrict__ conv_b,
    float* __restrict__ out) {
    __shared__ float w_lds[32 * 96];
    __shared__ float g_lds[32 * 64];
    __shared__ int   rowoff[64][4];
    __shared__ float rowwf[64][4];
    __shared__ int   colidx[64][4];
    __shared__ float colwf[64][4];
    const int tid = threadIdx.x;
    const int bin = blockIdx.x >> 4;
    const int rg  = blockIdx.x & 15;
    const int u = bin / KGRID, v = bin % KGRID;
    const int r0 = rg * 64;
    if (tid < 64) {
        const float4 reg = *(const float4*)(regions + (size_t)(r0 + tid) * 4);
        const float top  = (reg.x - reg.z * 0.5f) * (float)HH;
        const float left = (reg.y - reg.w * 0.5f) * (float)WW;
        const float bh = reg.z * ((float)HH / (float)KGRID);
        const float bw = reg.w * ((float)WW / (float)KGRID);
        const float scale = 1.0f / 196.0f;
#pragma unroll
        for (int s = 0; s < 2; s++) {
            const float off = (s + 0.5f) * 0.5f;
            float yy = top + ((float)u + off) * bh;
            yy = fminf(fmaxf(yy, 0.0f), (float)(HH - 1));
            const float y0f = floorf(yy);
            const int y0 = (int)y0f;
            const float wy1 = yy - y0f;
            rowoff[tid][2 * s] = y0 * WW;
            rowoff[tid][2 * s + 1] = min(y0 + 1, HH - 1) * WW;
            rowwf[tid][2 * s] = (1.0f - wy1) * scale;
            rowwf[tid][2 * s + 1] = wy1 * scale;
            float xx = left + ((float)v + off) * bw;
            xx = fminf(fmaxf(xx, 0.0f), (float)(WW - 1));
            const float x0f = floorf(xx);
            const int x0 = (int)x0f;
            const float wx1 = xx - x0f;
            colidx[tid][2 * s] = x0;
            colidx[tid][2 * s + 1] = min(x0 + 1, WW - 1);
            colwf[tid][2 * s] = 1.0f - wx1;
            colwf[tid][2 * s + 1] = wx1;
        }
    }
    const int ri = tid & 15, tq = tid >> 4, rb = tid >> 2, cq = tid & 3;
    float acc[4][6];
#pragma unroll
    for (int m = 0; m < 4; m++)
#pragma unroll
        for (int k = 0; k < 6; k++) acc[m][k] = 0.0f;
    for (int chunk = 0; chunk < IN_CH / 32; chunk++) {
        const int c0 = chunk * 32;
        __syncthreads();
#pragma unroll
        for (int it = 0; it < 12; it++) {
            const int idx = it * 256 + tid;
            const int t = idx >> 5, c = idx & 31;
            float val = 0.0f;
            if (t < NT) val = conv_w[(size_t)(t * NBINS + bin) * IN_CH + c0 + c];
            w_lds[c * 96 + t] = val;
        }
        const int cbase = c0 + cq * 8;
        float g8[8];
#pragma unroll
        for (int cc = 0; cc < 8; cc++) g8[cc] = 0.0f;
#pragma unroll
        for (int i = 0; i < 4; i++) {
            const int ro = rowoff[rb][i];
            const float wy = rowwf[rb][i];
#pragma unroll
            for (int j = 0; j < 4; j++) {
                const int pix = ro + colidx[rb][j];
                const float wv = wy * colwf[rb][j];
                if (XPOSED) {
                    const float4* p = (const float4*)(xsrc + (size_t)pix * IN_CH + cbase);
                    const float4 a = p[0]; const float4 b = p[1];
                    g8[0] += wv * a.x; g8[1] += wv * a.y; g8[2] += wv * a.z; g8[3] += wv * a.w;
                    g8[4] += wv * b.x; g8[5] += wv * b.y; g8[6] += wv * b.z; g8[7] += wv * b.w;
                } else {
#pragma unroll
                    for (int cc = 0; cc < 8; cc++)
                        g8[cc] += wv * xsrc[(size_t)(cbase + cc) * NPIX + pix];
                }
            }
        }
#pragma unroll
        for (int cc = 0; cc < 8; cc++) g_lds[(cq * 8 + cc) * 64 + rb] = g8[cc];
        __syncthreads();
#pragma unroll 4
        for (int c = 0; c < 32; c++) {
            float wv[6];
#pragma unroll
            for (int k = 0; k < 6; k++) wv[k] = w_lds[c * 96 + tq * 6 + k];
            const float4 gq = *(const float4*)&g_lds[c * 64 + ri * 4];
            const float gm[4] = {gq.x, gq.y, gq.z, gq.w};
#pragma unroll
            for (int m = 0; m < 4; m++)
#pragma unroll
                for (int k = 0; k < 6; k++) acc[m][k] += gm[m] * wv[k];
        }
    }
    const float invK2 = 1.0f / 49.0f;
#pragma unroll
    for (int k = 0; k < 6; k++) {
        const int t = tq * 6 + k;
        if (t < NT) {
            const float bterm = conv_b[t * NBINS + bin] * invK2;
#pragma unroll
            for (int m = 0; m < 4; m++) {
                const int rr = r0 + ri * 4 + m;
                atomicAdd(&out[(size_t)rr * NT + t], acc[m][k] + bterm);
            }
        }
    }
}

extern "C" void kernel_launch(void* const* d_in, const int* in_sizes, int n_in,
                              void* d_out, int out_size, void* d_ws, size_t ws_size,
                              hipStream_t stream) {
    const float* x       = (const float*)d_in[0];
    const float* regions = (const float*)d_in[1];
    const float* conv_w  = (const float*)d_in[2];
    const float* conv_b  = (const float*)d_in[3];
    float* out = (float*)d_out;

    const size_t sz_xbT = (size_t)NPIX * IN_CH * 2;          // 20,480,000
    const size_t sz_Wr  = (size_t)NPADW * IN_CH * 2;         //  8,388,608
    const size_t sz_sm  = (size_t)NPIX * SROWB + 256;        // 41,160,000 + slack
    const size_t sz_sc  = (size_t)NSC * sizeof(float);       // 10,240
    const size_t need   = sz_xbT + sz_Wr + sz_sm + sz_sc;    // ~70.0 MB

    if (ws_size >= need) {
        ushortT* xbT = (ushortT*)d_ws;
        ushortT* Wr  = (ushortT*)((char*)d_ws + sz_xbT);
        unsigned char* sm = (unsigned char*)d_ws + sz_xbT + sz_Wr;
        float* scales = (float*)((char*)d_ws + sz_xbT + sz_Wr + sz_sm);
        prep_fused<<<dim3(PREPG), 256, 0, stream>>>(x, xbT, conv_w, Wr);
        gemm_sm<<<dim3(GM_T * GN_T), 512, 0, stream>>>(xbT, Wr, sm, scales);
        pool_kernel<<<dim3(NREG), 256, 0, stream>>>(sm, scales, regions, conv_b, out);
    } else {
        hipMemsetAsync(out, 0, (size_t)out_size * sizeof(float), stream);
        const size_t xt_bytes = (size_t)NPIX * IN_CH * sizeof(float);
        const dim3 mainGrid(NBINS * 16);
        if (ws_size >= xt_bytes) {
            float* xt = (float*)d_ws;
            xpose_kernel<<<dim3((NPIX + 31) / 32, IN_CH / 32), dim3(32, 8), 0, stream>>>(x, xt);
            psroi_kernel<true><<<mainGrid, 256, 0, stream>>>(xt, regions, conv_w, conv_b, out);
        } else {
            psroi_kernel<false><<<mainGrid, 256, 0, stream>>>(x, regions, conv_w, conv_b, out);
        }
    }
}

// Round 8
// 211.885 us; speedup vs baseline: 5.3771x; 1.0776x over previous
//
#include <hip/hip_runtime.h>
#include <cstddef>

#define IN_CH 1024
#define NT    81
#define KGRID 7
#define NBINS 49
#define HH    100
#define WW    100
#define NPIX  (HH*WW)
#define NREG  1024
#define COLB  82            // gemm column group per bin: 81 real + 1 zero pad
#define NCOL  (NBINS*COLB)  // 4018 gemm columns
#define NPADW 4096          // padded N (16 tiles of 256)
#define SBIN  84            // sm per-bin stride in BYTES (int8), 4-aligned rows
#define SROWB (NBINS*SBIN)  // 4116 B per pixel row
#define NSC   2560          // scale table floats (80*32)
#define PXB   ((NPIX + 31) / 32)        // 313 prep_x col-blocks
#define PXG   (PXB * (IN_CH / 128))     // 2504 prep_x blocks
#define PREPG (PXG + NPADW / 8)         // + 512 prep_w blocks (8 rows each)

#define GM_T  40            // m tiles of 256 (10240 >= 10000)
#define GN_T  16            // n tiles of 256
#define NKT   16            // K tiles of 64 (K=1024)

typedef unsigned short ushortT;
typedef short bf16x8 __attribute__((ext_vector_type(8)));
typedef float f32x4  __attribute__((ext_vector_type(4)));

static __device__ __forceinline__ unsigned short f2bf(float f) {
    unsigned int u = __builtin_bit_cast(unsigned int, f);
    return (unsigned short)((u + 0x7fffu + ((u >> 16) & 1u)) >> 16);
}

// async global->LDS, 16B per lane; LDS dest = wave-uniform base + lane*16
static __device__ __forceinline__ void gld_lds16(const ushortT* g, ushortT* l) {
    __builtin_amdgcn_global_load_lds(
        (__attribute__((address_space(1))) void*)(unsigned long long)(uintptr_t)g,
        (__attribute__((address_space(3))) void*)(unsigned int)(unsigned long long)(uintptr_t)l,
        16, 0, 0);
}

static __device__ __forceinline__ void barf() {
    asm volatile("" ::: "memory");
    __builtin_amdgcn_s_barrier();
    asm volatile("" ::: "memory");
}

// ---------- fused prep: x (C,P) fp32 -> xbT (P,C) bf16  |  conv_w -> Wr -------------
// R7->R8: x loads vectorized float4 (G13) — 16 scalar loads/thread -> 4x float4.
// Slow path only for the 8 blocks covering pixels >= 9984. tile layout/repack
// byte-identical to previous rounds.
__global__ __launch_bounds__(256) void prep_fused(const float* __restrict__ x,
                                                  ushortT* __restrict__ xbT,
                                                  const float* __restrict__ conv_w,
                                                  ushortT* __restrict__ Wr) {
    __shared__ float tile[128][33];
    const int tid = threadIdx.x;
    const int bid = blockIdx.x;
    if (bid < PXG) {
        const int p0 = (bid % PXB) * 32;
        const int c0 = (bid / PXB) * 128;
        const int pq = tid & 7;           // pixel quad 0..7 -> pixels pq*4..pq*4+3
        const int cz = tid >> 3;          // 0..31
        const int p  = p0 + pq * 4;
        if (p0 + 32 <= NPIX) {
#pragma unroll
            for (int it = 0; it < 4; ++it) {
                const int c = it * 32 + cz;
                const float4 v = *(const float4*)(x + (size_t)(c0 + c) * NPIX + p);
                tile[c][pq * 4 + 0] = v.x;
                tile[c][pq * 4 + 1] = v.y;
                tile[c][pq * 4 + 2] = v.z;
                tile[c][pq * 4 + 3] = v.w;
            }
        } else {
#pragma unroll
            for (int it = 0; it < 4; ++it) {
                const int c = it * 32 + cz;
#pragma unroll
                for (int k = 0; k < 4; ++k)
                    tile[c][pq * 4 + k] = (p + k < NPIX) ? x[(size_t)(c0 + c) * NPIX + p + k] : 0.0f;
            }
        }
        __syncthreads();
#pragma unroll
        for (int pass = 0; pass < 2; ++pass) {
            const int pix = pass * 16 + (tid >> 4);
            const int cb  = (tid & 15) * 8;
            if (p0 + pix < NPIX) {
                uint4 pk;
                pk.x = (unsigned int)f2bf(tile[cb + 0][pix]) | ((unsigned int)f2bf(tile[cb + 1][pix]) << 16);
                pk.y = (unsigned int)f2bf(tile[cb + 2][pix]) | ((unsigned int)f2bf(tile[cb + 3][pix]) << 16);
                pk.z = (unsigned int)f2bf(tile[cb + 4][pix]) | ((unsigned int)f2bf(tile[cb + 5][pix]) << 16);
                pk.w = (unsigned int)f2bf(tile[cb + 6][pix]) | ((unsigned int)f2bf(tile[cb + 7][pix]) << 16);
                *(uint4*)(xbT + (size_t)(p0 + pix) * IN_CH + c0 + cb) = pk;
            }
        }
    } else {
        const int row0 = (bid - PXG) * 8;
        const int c    = tid * 4;
#pragma unroll
        for (int rr = 0; rr < 8; ++rr) {
            const int row = row0 + rr;
            const int bin = row / COLB;
            const int t   = row - bin * COLB;
            uint2 pk; pk.x = 0; pk.y = 0;
            if (bin < NBINS && t < NT) {
                const float4 v = *(const float4*)(conv_w + ((size_t)(t * NBINS + bin)) * IN_CH + c);
                pk.x = (unsigned int)f2bf(v.x) | ((unsigned int)f2bf(v.y) << 16);
                pk.y = (unsigned int)f2bf(v.z) | ((unsigned int)f2bf(v.w) << 16);
            }
            *(uint2*)(Wr + (size_t)row * IN_CH + c) = pk;
        }
    }
}

// ---------- GEMM: 256x256 tile, BK=64, 8 waves — R3 single-barrier variant ----------
// Session-best gemm (103us, MfmaUtil 35, conflicts 0, VGPR 128+128acc = at the
// 2-wave/SIMD cap). At 834 TF = 98.4% of the m248 reference (848 TF) for this exact
// structure/shape — plain-HIP structural ceiling. Resource walls documented:
// LDS||MFMA overlap needs +32 VGPR (cap) or more waves (LDS cap); BK=128 chunk
// needs 256KB LDS (cap). Do not re-tune the schedule; R1-R6 variants all in
// 102-112us. launch_bounds MUST stay (512,2) — R6: (512,4) spilled acc, 10x loss.
__global__ __launch_bounds__(512, 2) void gemm_sm(const ushortT* __restrict__ xbT,
                                                  const ushortT* __restrict__ Wr,
                                                  unsigned char* __restrict__ sm,
                                                  float* __restrict__ scales) {
    __shared__ ushortT lA[2][16384];   // [buf][256 rows][64 cols] swizzled
    __shared__ ushortT lB[2][16384];

    const int tid  = threadIdx.x;
    const int lane = tid & 63;
    const int w    = tid >> 6;        // 0..7
    const int wm   = w & 1;           // m half (128 rows)
    const int wn   = w >> 1;          // 0..3 (64 cols)

    // bijective XCD swizzle: 640 = 8 * 80
    const int bid   = blockIdx.x;
    const int sw    = (bid & 7) * 80 + (bid >> 3);
    const int mtile = sw >> 4;        // 0..39
    const int ntile = sw & 15;        // 0..15
    const int p0 = mtile * 256;
    const int n0 = ntile * 256;

    // ---- staging geometry (linear LDS dest, inverse-swizzled global source) ----
    const int l3   = lane >> 3;                       // 0..7 = row&7 of staged row
    const int srco = ((lane & 7) ^ l3) << 3;          // source col element offset
    const int w2   = w * 2;

    const ushortT* gA[2][2];
    const ushortT* gB[2][2];
    int dstA[2][2];
#pragma unroll
    for (int h = 0; h < 2; ++h)
#pragma unroll
        for (int it = 0; it < 2; ++it) {
            const int hr = (w2 + it) * 8 + l3;        // 0..127 within half
            int p = p0 + h * 128 + hr; if (p > NPIX - 1) p = NPIX - 1;
            gA[h][it] = xbT + (size_t)p * IN_CH + srco;
            gB[h][it] = Wr + (size_t)(n0 + h * 128 + hr) * IN_CH + srco;
            dstA[h][it] = h * 8192 + (w2 + it) * 512 + lane * 8;
        }

#define STAGE_A(bb, h, T) { gld_lds16(gA[h][0] + (size_t)(T) * 64, &lA[bb][dstA[h][0]]); \
                            gld_lds16(gA[h][1] + (size_t)(T) * 64, &lA[bb][dstA[h][1]]); }
#define STAGE_B(bb, h, T) { gld_lds16(gB[h][0] + (size_t)(T) * 64, &lB[bb][dstA[h][0]]); \
                            gld_lds16(gB[h][1] + (size_t)(T) * 64, &lB[bb][dstA[h][1]]); }

    // ---- fragment read geometry ----
    const int m_l = lane & 15;
    const int kq  = lane >> 4;                        // 0..3
    const int ph0 = ((kq) ^ (lane & 7)) << 3;         // kh=0 phys slot * 8
    const int ph1 = ((4 + kq) ^ (lane & 7)) << 3;     // kh=1
    const int arow = (wm * 128 + m_l) * 64;
    const int brow = (wn * 64 + m_l) * 64;

#define RD_A(bb, mq) { _Pragma("unroll") for (int mt = 0; mt < 4; ++mt) { \
        const int ro = arow + ((mq) * 64 + mt * 16) * 64; \
        af[mt][0] = *(const bf16x8*)(&lA[bb][ro + ph0]); \
        af[mt][1] = *(const bf16x8*)(&lA[bb][ro + ph1]); } }
#define RD_B(dst, bb, nq) { _Pragma("unroll") for (int nt = 0; nt < 2; ++nt) { \
        const int ro = brow + ((nq) * 32 + nt * 16) * 64; \
        dst[nt][0] = *(const bf16x8*)(&lB[bb][ro + ph0]); \
        dst[nt][1] = *(const bf16x8*)(&lB[bb][ro + ph1]); } }
#define MM(mq, B, nq) { _Pragma("unroll") for (int mt = 0; mt < 4; ++mt) \
        _Pragma("unroll") for (int nt = 0; nt < 2; ++nt) { \
        acc[mq][mt][nq][nt] = __builtin_amdgcn_mfma_f32_16x16x32_bf16(af[mt][0], B[nt][0], acc[mq][mt][nq][nt], 0, 0, 0); \
        acc[mq][mt][nq][nt] = __builtin_amdgcn_mfma_f32_16x16x32_bf16(af[mt][1], B[nt][1], acc[mq][mt][nq][nt], 0, 0, 0); } }

    f32x4 acc[2][4][2][2];
#pragma unroll
    for (int a = 0; a < 2; ++a)
#pragma unroll
        for (int b = 0; b < 4; ++b)
#pragma unroll
            for (int c = 0; c < 2; ++c)
#pragma unroll
                for (int d = 0; d < 2; ++d) acc[a][b][c][d] = (f32x4){0.f, 0.f, 0.f, 0.f};

    bf16x8 af[4][2], bf0[2][2], bf1[2][2];

    // ---- prologue: stage tiles 0 and 1 fully; wait tile 0 (tile 1 in flight) ----
    STAGE_A(0, 0, 0); STAGE_A(0, 1, 0); STAGE_B(0, 0, 0); STAGE_B(0, 1, 0);
    STAGE_A(1, 0, 1); STAGE_A(1, 1, 1); STAGE_B(1, 0, 1); STAGE_B(1, 1, 1);
    asm volatile("s_waitcnt vmcnt(8)" ::: "memory");
    __builtin_amdgcn_s_barrier();
    asm volatile("" ::: "memory");

#pragma unroll 2
    for (int kt = 0; kt < NKT; ++kt) {
        const int b = kt & 1;
        // ---- P1: reads A(mq0) + B(both nq); MM(0,0). no barrier ----
        RD_A(b, 0);
        RD_B(bf0, b, 0);
        RD_B(bf1, b, 1);
        __builtin_amdgcn_s_setprio(1);
        MM(0, bf0, 0);
        __builtin_amdgcn_s_setprio(0);
        // ---- P2: MM(0,1). barrier: all B-reads of buf b now consumed ----
        __builtin_amdgcn_s_setprio(1);
        MM(0, bf1, 1);
        __builtin_amdgcn_s_setprio(0);
        barf();
        // ---- P3: reads A(mq1); stage B(kt+2) into freed lB[b]; MM(1,1) ----
        RD_A(b, 1);
        if (kt < NKT - 2) { STAGE_B(b, 0, kt + 2); STAGE_B(b, 1, kt + 2); }
        __builtin_amdgcn_s_setprio(1);
        MM(1, bf1, 1);
        __builtin_amdgcn_s_setprio(0);
        barf();   // all A-reads of buf b consumed
        // ---- P4: MM(1,0); stage A(kt+2); counted vmcnt(8) ----
        __builtin_amdgcn_s_setprio(1);
        MM(1, bf0, 0);
        __builtin_amdgcn_s_setprio(0);
        if (kt < NKT - 2) {
            STAGE_A(b, 0, kt + 2); STAGE_A(b, 1, kt + 2);
            asm volatile("s_waitcnt vmcnt(8)" ::: "memory");
        } else {
            asm volatile("s_waitcnt vmcnt(0)" ::: "memory");
        }
        __builtin_amdgcn_s_barrier();
        asm volatile("" ::: "memory");
    }

    // ---- epilogue: per-quadrant (128x128) amax -> int8 quantize ----
    __syncthreads();
    float am = 0.0f;
#pragma unroll
    for (int mq = 0; mq < 2; ++mq)
#pragma unroll
        for (int mt = 0; mt < 4; ++mt)
#pragma unroll
            for (int nq = 0; nq < 2; ++nq)
#pragma unroll
                for (int nt = 0; nt < 2; ++nt)
#pragma unroll
                    for (int rg = 0; rg < 4; ++rg)
                        am = fmaxf(am, fabsf(acc[mq][mt][nq][nt][rg]));
#pragma unroll
    for (int off = 32; off > 0; off >>= 1) am = fmaxf(am, __shfl_xor(am, off));
    float* red = (float*)lA;
    if (lane == 0) red[w] = am;
    __syncthreads();
    // quadrant of wave w: (qm = wm, qn = wn>>1); partner wave = w ^ 2
    const float qam = fmaxf(fmaxf(red[w], red[w ^ 2]), 1e-30f);
    const float inv = 127.0f / qam;
    if (lane == 0 && (wn & 1) == 0)
        scales[(mtile * 2 + wm) * 32 + ntile * 2 + (wn >> 1)] = qam * (1.0f / 127.0f);

    const int prow0 = p0 + wm * 128 + kq * 4;
    const int ncol0 = n0 + wn * 64 + m_l;
    int  coloff[2][2];
    bool cok[2][2];
#pragma unroll
    for (int nq = 0; nq < 2; ++nq)
#pragma unroll
        for (int nt = 0; nt < 2; ++nt) {
            const int n = ncol0 + nq * 32 + nt * 16;
            cok[nq][nt] = (n < NCOL);
            coloff[nq][nt] = n + 2 * (n / COLB);
        }
#pragma unroll
    for (int mq = 0; mq < 2; ++mq)
#pragma unroll
        for (int mt = 0; mt < 4; ++mt)
#pragma unroll
            for (int rg = 0; rg < 4; ++rg) {
                const int p = prow0 + mq * 64 + mt * 16 + rg;
                if (p < NPIX) {
                    unsigned char* rowp = sm + (size_t)p * SROWB;
#pragma unroll
                    for (int nq = 0; nq < 2; ++nq)
#pragma unroll
                        for (int nt = 0; nt < 2; ++nt)
                            if (cok[nq][nt]) {
                                const int q = __float2int_rn(acc[mq][mt][nq][nt][rg] * inv);
                                rowp[coloff[nq][nt]] = (unsigned char)(signed char)q;
                            }
                }
            }
#undef STAGE_A
#undef STAGE_B
#undef RD_A
#undef RD_B
#undef MM
}

// ---------- pooling: ONE block per region -------------------------------------------
__global__ __launch_bounds__(256) void pool_kernel(const unsigned char* __restrict__ sm,
                                                   const float* __restrict__ scales,
                                                   const float* __restrict__ regions,
                                                   const float* __restrict__ conv_b,
                                                   float* __restrict__ out) {
    __shared__ int   rowo[28]; __shared__ float roww[28];
    __shared__ int   coli[28]; __shared__ float colw[28];
    __shared__ int   pofs[800];
    __shared__ float pw[800];
    __shared__ int   pptb[800];   // (pix>>7)*32
    __shared__ int   pnb[800];    // bin*82
    __shared__ float part[40][100];
    const int tid = threadIdx.x;
    const int r = blockIdx.x;

    if (tid < 28) {
        const float4 reg = *(const float4*)(regions + (size_t)r * 4);
        const float top = (reg.x - reg.z * 0.5f) * (float)HH;
        const float bh  = reg.z * ((float)HH / (float)KGRID);
        const int u = tid >> 2, i = tid & 3;
        const int s = i >> 1, hi = i & 1;
        float y = top + ((float)u + ((float)s + 0.5f) * 0.5f) * bh;
        y = fminf(fmaxf(y, 0.0f), (float)(HH - 1));
        const float y0f = floorf(y);
        const int y0 = (int)y0f;
        const float wy1 = y - y0f;
        rowo[tid] = (hi ? min(y0 + 1, HH - 1) : y0) * WW;
        roww[tid] = hi ? wy1 : (1.0f - wy1);
    } else if (tid >= 32 && tid < 60) {
        const float4 reg = *(const float4*)(regions + (size_t)r * 4);
        const float left = (reg.y - reg.w * 0.5f) * (float)WW;
        const float bw   = reg.w * ((float)WW / (float)KGRID);
        const int idx = tid - 32;
        const int v = idx >> 2, j = idx & 3;
        const int s = j >> 1, hi = j & 1;
        float xx = left + ((float)v + ((float)s + 0.5f) * 0.5f) * bw;
        xx = fminf(fmaxf(xx, 0.0f), (float)(WW - 1));
        const float x0f = floorf(xx);
        const int x0 = (int)x0f;
        const float wx1 = xx - x0f;
        coli[idx] = hi ? min(x0 + 1, WW - 1) : x0;
        colw[idx] = hi ? wx1 : (1.0f - wx1);
    }
    __syncthreads();
#pragma unroll
    for (int base = 0; base < 800; base += 256) {
        const int idx = base + tid;
        if (idx < 800) {
            if (idx < 784) {                 // 49 bins * 16 taps
                const int bin = idx >> 4, tap = idx & 15;
                const int u = bin / KGRID, v = bin - u * KGRID;
                const int i = tap >> 2, j = tap & 3;
                const int pix = rowo[u * 4 + i] + coli[v * 4 + j];
                pofs[idx] = pix * SROWB + bin * SBIN;     // BYTE offset, 4-aligned
                pw[idx]   = roww[u * 4 + i] * colw[v * 4 + j] * (1.0f / 196.0f);
                pptb[idx] = (pix >> 7) * 32;
                pnb[idx]  = bin * COLB;
            } else {                          // zero-weight padding taps
                pofs[idx] = 0;
                pw[idx]   = 0.0f;
                pptb[idx] = 0;
                pnb[idx]  = 0;
            }
        }
    }
    __syncthreads();

    const int lane = tid & 63, w = tid >> 6;
    const int sub  = lane / 6;              // 0..9 active, lanes 60..63 idle
    const int cg   = lane - sub * 6;        // 0..5 -> channels cg*16..+15
    if (sub < 10) {
        const int str = w * 10 + sub;       // 0..39

        float acc[16];
#pragma unroll
        for (int ch = 0; ch < 16; ++ch) acc[ch] = 0.0f;

        uint4 v[4], vn[4];
#pragma unroll
        for (int it = 0; it < 4; ++it)
            v[it] = *(const uint4*)(sm + pofs[it * 40 + str] + cg * 16);

        for (int gp = 0; gp < 5; ++gp) {
            if (gp < 4) {
#pragma unroll
                for (int it = 0; it < 4; ++it)
                    vn[it] = *(const uint4*)(sm + pofs[(gp * 4 + 4 + it) * 40 + str] + cg * 16);
            }
#pragma unroll
            for (int it = 0; it < 4; ++it) {
                const int l  = (gp * 4 + it) * 40 + str;
                const float wt = pw[l];
                const int nb  = pnb[l] + cg * 16;   // n of channel 0
                const int nt0 = nb >> 7;
                const int rr  = nb & 127;
                const float s0 = scales[pptb[l] + nt0];
                const float s1 = scales[pptb[l] + nt0 + 1];
                const float w0 = wt * s0, w1 = wt * s1;
                const unsigned int uu[4] = {v[it].x, v[it].y, v[it].z, v[it].w};
#pragma unroll
                for (int b = 0; b < 4; ++b) {
#pragma unroll
                    for (int k = 0; k < 4; ++k) {
                        const int ch = b * 4 + k;
                        const int q = (int)(signed char)((uu[b] >> (k * 8)) & 0xff);
                        acc[ch] += ((rr < 128 - ch) ? w0 : w1) * (float)q;
                    }
                }
            }
#pragma unroll
            for (int it = 0; it < 4; ++it) v[it] = vn[it];
        }
#pragma unroll
        for (int b = 0; b < 4; ++b) {
            float4 p4;
            p4.x = acc[b * 4]; p4.y = acc[b * 4 + 1];
            p4.z = acc[b * 4 + 2]; p4.w = acc[b * 4 + 3];
            *(float4*)&part[str][cg * 16 + b * 4] = p4;
        }
    }
    __syncthreads();
    if (tid < NT) {
        float vv = 0.f;
#pragma unroll
        for (int s = 0; s < 40; ++s) vv += part[s][tid];
        float bsum = 0.f;
        for (int bin = 0; bin < NBINS; ++bin) bsum += conv_b[tid * NBINS + bin];
        out[(size_t)r * NT + tid] = vv + bsum * (1.0f / (float)NBINS);
    }
}

// =======================  fallback path (round-1 kernel)  ==========================
__global__ __launch_bounds__(256) void xpose_kernel(const float* __restrict__ x,
                                                    float* __restrict__ xt) {
    __shared__ float tile[32][33];
    const int p0 = blockIdx.x * 32;
    const int c0 = blockIdx.y * 32;
    const int tx = threadIdx.x;
    const int ty = threadIdx.y;
#pragma unroll
    for (int k = 0; k < 32; k += 8) {
        const int p = p0 + tx;
        if (p < NPIX) tile[ty + k][tx] = x[(size_t)(c0 + ty + k) * NPIX + p];
    }
    __syncthreads();
#pragma unroll
    for (int k = 0; k < 32; k += 8) {
        const int p = p0 + ty + k;
        if (p < NPIX) xt[(size_t)p * IN_CH + (c0 + tx)] = tile[tx][ty + k];
    }
}

template <bool XPOSED>
__global__ __launch_bounds__(256) void psroi_kernel(
    const float* __restrict__ xsrc, const float* __restrict__ regions,
    const float* __restrict__ conv_w, const float* __restrict__ conv_b,
    float* __restrict__ out) {
    __shared__ float w_lds[32 * 96];
    __shared__ float g_lds[32 * 64];
    __shared__ int   rowoff[64][4];
    __shared__ float rowwf[64][4];
    __shared__ int   colidx[64][4];
    __shared__ float colwf[64][4];
    const int tid = threadIdx.x;
    const int bin = blockIdx.x >> 4;
    const int rg  = blockIdx.x & 15;
    const int u = bin / KGRID, v = bin % KGRID;
    const int r0 = rg * 64;
    if (tid < 64) {
        const float4 reg = *(const float4*)(regions + (size_t)(r0 + tid) * 4);
        const float top  = (reg.x - reg.z * 0.5f) * (float)HH;
        const float left = (reg.y - reg.w * 0.5f) * (float)WW;
        const float bh = reg.z * ((float)HH / (float)KGRID);
        const float bw = reg.w * ((float)WW / (float)KGRID);
        const float scale = 1.0f / 196.0f;
#pragma unroll
        for (int s = 0; s < 2; s++) {
            const float off = (s + 0.5f) * 0.5f;
            float yy = top + ((float)u + off) * bh;
            yy = fminf(fmaxf(yy, 0.0f), (float)(HH - 1));
            const float y0f = floorf(yy);
            const int y0 = (int)y0f;
            const float wy1 = yy - y0f;
            rowoff[tid][2 * s] = y0 * WW;
            rowoff[tid][2 * s + 1] = min(y0 + 1, HH - 1) * WW;
            rowwf[tid][2 * s] = (1.0f - wy1) * scale;
            rowwf[tid][2 * s + 1] = wy1 * scale;
            float xx = left + ((float)v + off) * bw;
            xx = fminf(fmaxf(xx, 0.0f), (float)(WW - 1));
            const float x0f = floorf(xx);
            const int x0 = (int)x0f;
            const float wx1 = xx - x0f;
            colidx[tid][2 * s] = x0;
            colidx[tid][2 * s + 1] = min(x0 + 1, WW - 1);
            colwf[tid][2 * s] = 1.0f - wx1;
            colwf[tid][2 * s + 1] = wx1;
        }
    }
    const int ri = tid & 15, tq = tid >> 4, rb = tid >> 2, cq = tid & 3;
    float acc[4][6];
#pragma unroll
    for (int m = 0; m < 4; m++)
#pragma unroll
        for (int k = 0; k < 6; k++) acc[m][k] = 0.0f;
    for (int chunk = 0; chunk < IN_CH / 32; chunk++) {
        const int c0 = chunk * 32;
        __syncthreads();
#pragma unroll
        for (int it = 0; it < 12; it++) {
            const int idx = it * 256 + tid;
            const int t = idx >> 5, c = idx & 31;
            float val = 0.0f;
            if (t < NT) val = conv_w[(size_t)(t * NBINS + bin) * IN_CH + c0 + c];
            w_lds[c * 96 + t] = val;
        }
        const int cbase = c0 + cq * 8;
        float g8[8];
#pragma unroll
        for (int cc = 0; cc < 8; cc++) g8[cc] = 0.0f;
#pragma unroll
        for (int i = 0; i < 4; i++) {
            const int ro = rowoff[rb][i];
            const float wy = rowwf[rb][i];
#pragma unroll
            for (int j = 0; j < 4; j++) {
                const int pix = ro + colidx[rb][j];
                const float wv = wy * colwf[rb][j];
                if (XPOSED) {
                    const float4* p = (const float4*)(xsrc + (size_t)pix * IN_CH + cbase);
                    const float4 a = p[0]; const float4 b = p[1];
                    g8[0] += wv * a.x; g8[1] += wv * a.y; g8[2] += wv * a.z; g8[3] += wv * a.w;
                    g8[4] += wv * b.x; g8[5] += wv * b.y; g8[6] += wv * b.z; g8[7] += wv * b.w;
                } else {
#pragma unroll
                    for (int cc = 0; cc < 8; cc++)
                        g8[cc] += wv * xsrc[(size_t)(cbase + cc) * NPIX + pix];
                }
            }
        }
#pragma unroll
        for (int cc = 0; cc < 8; cc++) g_lds[(cq * 8 + cc) * 64 + rb] = g8[cc];
        __syncthreads();
#pragma unroll 4
        for (int c = 0; c < 32; c++) {
            float wv[6];
#pragma unroll
            for (int k = 0; k < 6; k++) wv[k] = w_lds[c * 96 + tq * 6 + k];
            const float4 gq = *(const float4*)&g_lds[c * 64 + ri * 4];
            const float gm[4] = {gq.x, gq.y, gq.z, gq.w};
#pragma unroll
            for (int m = 0; m < 4; m++)
#pragma unroll
                for (int k = 0; k < 6; k++) acc[m][k] += gm[m] * wv[k];
        }
    }
    const float invK2 = 1.0f / 49.0f;
#pragma unroll
    for (int k = 0; k < 6; k++) {
        const int t = tq * 6 + k;
        if (t < NT) {
            const float bterm = conv_b[t * NBINS + bin] * invK2;
#pragma unroll
            for (int m = 0; m < 4; m++) {
                const int rr = r0 + ri * 4 + m;
                atomicAdd(&out[(size_t)rr * NT + t], acc[m][k] + bterm);
            }
        }
    }
}

extern "C" void kernel_launch(void* const* d_in, const int* in_sizes, int n_in,
                              void* d_out, int out_size, void* d_ws, size_t ws_size,
                              hipStream_t stream) {
    const float* x       = (const float*)d_in[0];
    const float* regions = (const float*)d_in[1];
    const float* conv_w  = (const float*)d_in[2];
    const float* conv_b  = (const float*)d_in[3];
    float* out = (float*)d_out;

    const size_t sz_xbT = (size_t)NPIX * IN_CH * 2;          // 20,480,000
    const size_t sz_Wr  = (size_t)NPADW * IN_CH * 2;         //  8,388,608
    const size_t sz_sm  = (size_t)NPIX * SROWB + 256;        // 41,160,000 + slack
    const size_t sz_sc  = (size_t)NSC * sizeof(float);       // 10,240
    const size_t need   = sz_xbT + sz_Wr + sz_sm + sz_sc;    // ~70.0 MB

    if (ws_size >= need) {
        ushortT* xbT = (ushortT*)d_ws;
        ushortT* Wr  = (ushortT*)((char*)d_ws + sz_xbT);
        unsigned char* sm = (unsigned char*)d_ws + sz_xbT + sz_Wr;
        float* scales = (float*)((char*)d_ws + sz_xbT + sz_Wr + sz_sm);
        prep_fused<<<dim3(PREPG), 256, 0, stream>>>(x, xbT, conv_w, Wr);
        gemm_sm<<<dim3(GM_T * GN_T), 512, 0, stream>>>(xbT, Wr, sm, scales);
        pool_kernel<<<dim3(NREG), 256, 0, stream>>>(sm, scales, regions, conv_b, out);
    } else {
        hipMemsetAsync(out, 0, (size_t)out_size * sizeof(float), stream);
        const size_t xt_bytes = (size_t)NPIX * IN_CH * sizeof(float);
        const dim3 mainGrid(NBINS * 16);
        if (ws_size >= xt_bytes) {
            float* xt = (float*)d_ws;
            xpose_kernel<<<dim3((NPIX + 31) / 32, IN_CH / 32), dim3(32, 8), 0, stream>>>(x, xt);
            psroi_kernel<true><<<mainGrid, 256, 0, stream>>>(xt, regions, conv_w, conv_b, out);
        } else {
            psroi_kernel<false><<<mainGrid, 256, 0, stream>>>(x, regions, conv_w, conv_b, out);
        }
    }
}